// Round 17
// baseline (126.055 us; speedup 1.0000x reference)
//
#include <hip/hip_runtime.h>

// Problem constants
#define MM 15   // max_peptide_size
#define RR 64   // aa_rep_size
#define PP 34   // pocket positions
#define FF 9    // filter size
#define AA 20   // alphabet size
#define OW 72   // RR + FF - 1

// DPP controls (GFX9-family): whole-wave shift by one lane
#define WAVE_SHL1 0x130
#define WAVE_SHR1 0x138

// wave_shr1: result[lane] = src[lane-1], lane 0 -> 0 (bound_ctrl)
__device__ __forceinline__ float dpp_shr1(float x) {
    return __int_as_float(__builtin_amdgcn_update_dpp(
        0, __float_as_int(x), WAVE_SHR1, 0xF, 0xF, true));
}
// wave_shl1: result[lane] = src[lane+1], lane 63 -> 0 (bound_ctrl)
__device__ __forceinline__ float dpp_shl1(float x) {
    return __int_as_float(__builtin_amdgcn_update_dpp(
        0, __float_as_int(x), WAVE_SHL1, 0xF, 0xF, true));
}

// ONE SAMPLE PER WAVE: 4 samples per 256-thread block, grid = B/4.
// Zero LDS, zero barriers, no SALU compare chains. Lane = representation r.
// Per row p: s = sum_m (float)adj[m] * pv[m]  (3 parallel partial chains),
// then 9-tap full conv via two DPP shift recurrences (pure VALU).
__global__ __launch_bounds__(256)
void ppc_kernel(const float* __restrict__ pe,      // [B, M, R]
                const int*   __restrict__ idx,     // [B, P]
                const int*   __restrict__ adj,     // [B, P, M]
                const float* __restrict__ kernels, // [A, F]
                float*       __restrict__ out)     // [B, P, OW]
{
    const int b    = (blockIdx.x << 2) | (threadIdx.x >> 6);  // sample id
    const int lane = threadIdx.x & 63;

    const float* peb  = pe  + (size_t)b * (MM * RR);
    const int*   adjb = adj + (size_t)b * (PP * MM);
    const int*   idxb = idx + (size_t)b * PP;
    float*       outb = out + (size_t)b * (PP * OW);

    // this wave's pe column (coalesced 256 B/inst; each sample read ONCE)
    float pv[MM];
    #pragma unroll
    for (int m = 0; m < MM; ++m) pv[m] = peb[m * RR + lane];

    // 34 independent row-chains; unroll 2 keeps two in flight for ILP
    #pragma unroll 2
    for (int p = 0; p < PP; ++p) {
        const int* g = adjb + p * MM;        // wave-uniform -> s_load
        // 3 parallel partial sums shorten the dependency chain (60 -> ~28 cy)
        float a0 = 0.f, a1 = 0.f, a2 = 0.f;
        #pragma unroll
        for (int m = 0; m < 5; ++m) a0 = fmaf((float)g[m],      pv[m],      a0);
        #pragma unroll
        for (int m = 0; m < 5; ++m) a1 = fmaf((float)g[5 + m],  pv[5 + m],  a1);
        #pragma unroll
        for (int m = 0; m < 5; ++m) a2 = fmaf((float)g[10 + m], pv[10 + m], a2);
        const float s = (a0 + a1) + a2;

        // filter taps: wave-uniform scalar loads -> SGPRs
        const float* kb = kernels + idxb[p] * FF;
        float kf[FF];
        #pragma unroll
        for (int i = 0; i < FF; ++i) kf[i] = kb[i];

        // main outputs o = lane (0..63):
        // H[r] = sum_{i=0..8} kf[i] * s[r-i]   (s[<0] = 0 via bound_ctrl)
        float H = kf[8] * s;
        #pragma unroll
        for (int i = 7; i >= 0; --i)
            H = fmaf(kf[i], s, dpp_shr1(H));
        outb[p * OW + lane] = H;             // 256 B coalesced store

        // tail outputs o = 64..71 (lanes 56..63, o = lane + 8):
        // T[r] = sum_{i=0..8} kf[i] * s[r+8-i] (s[>63] = 0 via bound_ctrl)
        float T = kf[0] * s;
        #pragma unroll
        for (int i = 1; i <= 8; ++i)
            T = fmaf(kf[i], s, dpp_shl1(T));
        if (lane >= 56)
            outb[p * OW + 8 + lane] = T;     // 32 B coalesced store
    }
}

extern "C" void kernel_launch(void* const* d_in, const int* in_sizes, int n_in,
                              void* d_out, int out_size, void* d_ws, size_t ws_size,
                              hipStream_t stream) {
    const float* pe      = (const float*)d_in[0]; // [B,M,R] f32
    const int*   idx     = (const int*)  d_in[1]; // [B,P]   i32
    const int*   adj     = (const int*)  d_in[2]; // [B,P,M] i32
    const float* kernels = (const float*)d_in[3]; // [A,F]   f32
    float*       out     = (float*)d_out;

    const int B = in_sizes[0] / (MM * RR);
    ppc_kernel<<<B / 4, 256, 0, stream>>>(pe, idx, adj, kernels, out);
}

// Round 21
// 85.494 us; speedup vs baseline: 1.4744x; 1.4744x over previous
//
#include <hip/hip_runtime.h>

// Problem constants
#define MM 15   // max_peptide_size
#define RR 64   // aa_rep_size
#define PP 34   // pocket positions
#define FF 9    // filter size
#define AA 20   // alphabet size
#define OW 72   // RR + FF - 1
#define AJ 16   // adj-float row stride in LDS

// DPP controls (GFX9-family): whole-wave shift by one lane
#define WAVE_SHL1 0x130
#define WAVE_SHR1 0x138

// wave_shr1: result[lane] = src[lane-1], lane 0 -> 0 (bound_ctrl)  [verified r16]
__device__ __forceinline__ float dpp_shr1(float x) {
    return __int_as_float(__builtin_amdgcn_update_dpp(
        0, __float_as_int(x), WAVE_SHR1, 0xF, 0xF, true));
}
// wave_shl1: result[lane] = src[lane+1], lane 63 -> 0 (bound_ctrl)  [verified r16]
__device__ __forceinline__ float dpp_shl1(float x) {
    return __int_as_float(__builtin_amdgcn_update_dpp(
        0, __float_as_int(x), WAVE_SHL1, 0xF, 0xF, true));
}

// One block per sample, 4 waves; wave w owns rows p = w + 4j (9 rows max).
// Gates: staged once to LDS as floats (coalesced VECTOR loads), then read as
// single-address broadcast b128 (no SMEM storm, no conflicts).
// s[p][r]: registers (lane = r). Conv: DPP shift recurrences (zero LDS).
__global__ __launch_bounds__(256)
void ppc_kernel(const float* __restrict__ pe,      // [B, M, R]
                const int*   __restrict__ idx,     // [B, P]
                const int*   __restrict__ adj,     // [B, P, M]
                const float* __restrict__ kernels, // [A, F]
                float*       __restrict__ out)     // [B, P, OW]
{
    const int b    = blockIdx.x;
    const int t    = threadIdx.x;
    const int lane = t & 63;
    const int w    = t >> 6;

    __shared__ float s_adjf[PP * AJ];   // 544 f = 2.2 KB (col 15 = 0)

    const float* peb  = pe  + (size_t)b * (MM * RR);
    const int*   adjb = adj + (size_t)b * (PP * MM);
    const int*   idxb = idx + (size_t)b * PP;
    float*       outb = out + (size_t)b * (PP * OW);

    // ---- stage adj -> LDS floats (coalesced vector path, 2 loads/thread)
    #pragma unroll
    for (int k = 0; k < 2; ++k) {
        const int i = t + k * 256;
        if (i < PP * MM) {
            const int p = (unsigned)i / MM, m = i - p * MM;
            s_adjf[p * AJ + m] = (float)adjb[i];
        }
    }
    if (t < PP) s_adjf[t * AJ + 15] = 0.0f;

    // per-lane pe column (coalesced; L1-shared across the 4 waves)
    float pv[MM];
    #pragma unroll
    for (int m = 0; m < MM; ++m) pv[m] = peb[m * RR + lane];

    __syncthreads();    // the only barrier

    #pragma unroll
    for (int j = 0; j < 9; ++j) {
        const int p = w + 4 * j;
        if (p < PP) {                      // wave-uniform
            // ---- Phase B: gates via broadcast b128 (single LDS address)
            const float* g = &s_adjf[p * AJ];
            const float4 g0 = *(const float4*)&g[0];
            const float4 g1 = *(const float4*)&g[4];
            const float4 g2 = *(const float4*)&g[8];
            const float4 g3 = *(const float4*)&g[12];   // .w == 0
            float a0, a1, a2;   // 3 parallel chains (short critical path)
            a0 = g0.x * pv[0];  a1 = g0.y * pv[1];  a2 = g0.z * pv[2];
            a0 = fmaf(g0.w, pv[3],  a0);
            a1 = fmaf(g1.x, pv[4],  a1);
            a2 = fmaf(g1.y, pv[5],  a2);
            a0 = fmaf(g1.z, pv[6],  a0);
            a1 = fmaf(g1.w, pv[7],  a1);
            a2 = fmaf(g2.x, pv[8],  a2);
            a0 = fmaf(g2.y, pv[9],  a0);
            a1 = fmaf(g2.z, pv[10], a1);
            a2 = fmaf(g2.w, pv[11], a2);
            a0 = fmaf(g3.x, pv[12], a0);
            a1 = fmaf(g3.y, pv[13], a1);
            a2 = fmaf(g3.z, pv[14], a2);
            const float s = (a0 + a1) + a2;

            // ---- taps: K$-hot scalar loads (kernels = 720 B resident)
            const float* kb = kernels + idxb[p] * FF;
            float kf[FF];
            #pragma unroll
            for (int i2 = 0; i2 < FF; ++i2) kf[i2] = kb[i2];

            // ---- main outputs o = lane: H[r] = sum_i kf[i]*s[r-i]
            float H = kf[8] * s;
            #pragma unroll
            for (int i2 = 7; i2 >= 0; --i2)
                H = fmaf(kf[i2], s, dpp_shr1(H));
            outb[p * OW + lane] = H;       // 288 B coalesced store

            // ---- tail o = 64..71 (lanes 56..63): T[r] = sum_i kf[i]*s[r+8-i]
            float T = kf[0] * s;
            #pragma unroll
            for (int i2 = 1; i2 <= 8; ++i2)
                T = fmaf(kf[i2], s, dpp_shl1(T));
            if (lane >= 56)
                outb[p * OW + 8 + lane] = T;
        }
    }
}

extern "C" void kernel_launch(void* const* d_in, const int* in_sizes, int n_in,
                              void* d_out, int out_size, void* d_ws, size_t ws_size,
                              hipStream_t stream) {
    const float* pe      = (const float*)d_in[0]; // [B,M,R] f32
    const int*   idx     = (const int*)  d_in[1]; // [B,P]   i32
    const int*   adj     = (const int*)  d_in[2]; // [B,P,M] i32
    const float* kernels = (const float*)d_in[3]; // [A,F]   f32
    float*       out     = (float*)d_out;

    const int B = in_sizes[0] / (MM * RR);
    ppc_kernel<<<B, 256, 0, stream>>>(pe, idx, adj, kernels, out);
}